// Round 12
// baseline (459.913 us; speedup 1.0000x reference)
//
#include <hip/hip_runtime.h>

// Problem constants (from reference)
#define B_  16
#define T_  2048
#define IN_ 512
#define H_  512
#define M_  (B_ * T_)

// GEMM tiling — R5/R10 structure, the measured optimum (205us, VGPR 116).
// History: R6 (256,4) bound -> acc spill -> 3048us. R7 2-reg-set ping-pong
// -> VGPR 192 -> 298us. R8 persistent fusion -> occupancy coupling -> 529us.
// R9 mid-compute staging -> vmcnt drain mid-tile -> 230us. R11 1-barrier
// alternating buffers -> 214us (worse). KEEP THIS EXACT STRUCTURE.
#define BM 128
#define BN 128
#define BK 16
#define LDT (BM + 4)

static __device__ __forceinline__ float4 ld4(const float* p) {
    return *reinterpret_cast<const float4*>(p);
}

// ---------------------------------------------------------------------------
// Kernel 1: h[m][n] = sum_k x[m][k]*W[n][k] + b[n], fp32 VALU.
// k accumulated strictly in order 0..511 with fmaf -> bit-matches np ref
// (absmax 0.0 across R2-R11). DO NOT reorder the k loop.
// Single LDS buffer + register prefetch of next k-tile (R10 body, verbatim).
// ---------------------------------------------------------------------------
__global__ __launch_bounds__(256)
void gemm_xwT(const float* __restrict__ X, const float* __restrict__ W,
              const float* __restrict__ bias, float* __restrict__ Hout) {
    __shared__ float As[BK][LDT];
    __shared__ float Bs[BK][LDT];

    const int tid = threadIdx.x;
    const int m0  = blockIdx.x * BM;   // 256 m-tiles
    const int n0  = blockIdx.y * BN;   // 4 n-tiles

    const int tx = tid & 15;           // col group
    const int ty = tid >> 4;           // row group

    const int row = tid >> 2;          // 0..63
    const int kph = (tid & 3) * 4;     // 0,4,8,12

    const float* pa0 = X + (size_t)(m0 + row) * IN_ + kph;
    const float* pa1 = pa0 + (size_t)64 * IN_;
    const float* pb0 = W + (size_t)(n0 + row) * IN_ + kph;
    const float* pb1 = pb0 + (size_t)64 * IN_;

    float4 ra0 = ld4(pa0), ra1 = ld4(pa1), rb0 = ld4(pb0), rb1 = ld4(pb1);

    float acc[8][8];
#pragma unroll
    for (int i = 0; i < 8; ++i)
#pragma unroll
        for (int j = 0; j < 8; ++j) acc[i][j] = 0.0f;

    for (int k0 = 0; k0 < IN_; k0 += BK) {
        As[kph + 0][row]      = ra0.x;  As[kph + 1][row]      = ra0.y;
        As[kph + 2][row]      = ra0.z;  As[kph + 3][row]      = ra0.w;
        As[kph + 0][row + 64] = ra1.x;  As[kph + 1][row + 64] = ra1.y;
        As[kph + 2][row + 64] = ra1.z;  As[kph + 3][row + 64] = ra1.w;
        Bs[kph + 0][row]      = rb0.x;  Bs[kph + 1][row]      = rb0.y;
        Bs[kph + 2][row]      = rb0.z;  Bs[kph + 3][row]      = rb0.w;
        Bs[kph + 0][row + 64] = rb1.x;  Bs[kph + 1][row + 64] = rb1.y;
        Bs[kph + 2][row + 64] = rb1.z;  Bs[kph + 3][row + 64] = rb1.w;
        __syncthreads();

        // prefetch next k-tile into registers; drains during the 16-k compute
        if (k0 + BK < IN_) {
            ra0 = ld4(pa0 + k0 + BK);  ra1 = ld4(pa1 + k0 + BK);
            rb0 = ld4(pb0 + k0 + BK);  rb1 = ld4(pb1 + k0 + BK);
        }

#pragma unroll
        for (int k = 0; k < BK; ++k) {
            float4 av0 = ld4(&As[k][ty * 4]);
            float4 av1 = ld4(&As[k][ty * 4 + 64]);
            float4 bv0 = ld4(&Bs[k][tx * 4]);
            float4 bv1 = ld4(&Bs[k][tx * 4 + 64]);
            const float am[8] = {av0.x, av0.y, av0.z, av0.w,
                                 av1.x, av1.y, av1.z, av1.w};
            const float bn8[8] = {bv0.x, bv0.y, bv0.z, bv0.w,
                                  bv1.x, bv1.y, bv1.z, bv1.w};
#pragma unroll
            for (int i = 0; i < 8; ++i)
#pragma unroll
                for (int j = 0; j < 8; ++j)
                    acc[i][j] = fmaf(am[i], bn8[j], acc[i][j]);
        }
        __syncthreads();
    }

    // epilogue: + bias (bias is zeros -> exact), coalesced float4 stores
    float4 bb0 = ld4(&bias[n0 + tx * 4]);
    float4 bb1 = ld4(&bias[n0 + tx * 4 + 64]);
#pragma unroll
    for (int i = 0; i < 8; ++i) {
        const int r = m0 + ((i < 4) ? (ty * 4 + i) : (64 + ty * 4 + (i - 4)));
        float4 o0, o1;
        o0.x = acc[i][0] + bb0.x;  o0.y = acc[i][1] + bb0.y;
        o0.z = acc[i][2] + bb0.z;  o0.w = acc[i][3] + bb0.w;
        o1.x = acc[i][4] + bb1.x;  o1.y = acc[i][5] + bb1.y;
        o1.z = acc[i][6] + bb1.z;  o1.w = acc[i][7] + bb1.w;
        *reinterpret_cast<float4*>(&Hout[(size_t)r * H_ + n0 + tx * 4])      = o0;
        *reinterpret_cast<float4*>(&Hout[(size_t)r * H_ + n0 + tx * 4 + 64]) = o1;
    }
}

// ---------------------------------------------------------------------------
// Kernel 2: GIF neuron scan — TWO independent chains per thread.
// R10/R11 established the scan is dependent-chain-latency-bound (~193 cyc
// period) with no single dominant op (removing fma: no change; removing
// rcp: worse). With 1 chain/thread there is zero independent work to fill
// latency bubbles. Fix: thread owns chains c and c+4096; their independent
// chains interleave in the instruction stream -> each chain's bubbles
// absorb the other's ops. Per-chain step arithmetic is VERBATIM R10
// (1 N-R + Markstein div; absmax 0.0) — DO NOT touch the statements.
// ---------------------------------------------------------------------------
#define SPF 16   // prefetch depth per chain (16 steps x ~150 cyc >> HBM lat)

__device__ __forceinline__
void gif_step(float cur, float& v, float& theta, float& s_out) {
    const float DECAY_F = 0.9048374180359595f;  // exp(-1/10)
    const float ALPHA_F = 0.01f;
    v = v * DECAY_F + cur;
    float cl = 32.0f * theta;                    // L * theta * 2
    v = __builtin_amdgcn_fmed3f(v, -cl, cl);     // == fminf(fmaxf(v,-cl),cl)

    // ---- correctly-rounded v/theta: rcp + 1 N-R + Markstein ----
    float r0 = __builtin_amdgcn_rcpf(theta);     // ~1 ulp
    float e0 = fmaf(-theta, r0, 1.0f);
    float r1 = fmaf(r0, e0, r0);                 // ~0.5 ulp reciprocal
    float q0 = v * r1;
    float er = fmaf(-theta, q0, v);              // exact residual
    float q  = fmaf(er, r1, q0);                 // correctly-rounded quotient
    // ------------------------------------------------------------

    float s = floorf(q);
    s = __builtin_amdgcn_fmed3f(s, 0.0f, 16.0f); // == fminf(fmaxf(s,0),16)
    v = v - s * theta;
    theta = theta + ALPHA_F * s - ALPHA_F * (theta - 1.0f);
    s_out = s;
}

__device__ __forceinline__
void scan_steps2(const float* __restrict__ b0, const float* __restrict__ b1,
                 float* __restrict__ sp0, float* __restrict__ sp1, int tb,
                 float& v0, float& th0, float& v1, float& th1) {
#pragma unroll
    for (int j = 0; j < SPF; ++j) {
        float s0, s1;
        gif_step(b0[j], v0, th0, s0);   // chain 0, step tb+j
        gif_step(b1[j], v1, th1, s1);   // chain 1, step tb+j (independent)
        sp0[(size_t)(tb + j) * H_] = s0;
        sp1[(size_t)(tb + j) * H_] = s1;
    }
}

__global__ __launch_bounds__(64)
void gif_scan(const float* __restrict__ Hbuf, float* __restrict__ spikes,
              float* __restrict__ vout, float* __restrict__ thout) {
    const int t0id = blockIdx.x * 64 + threadIdx.x;   // 0..4095
    const int c0 = t0id;                              // chain set 0
    const int c1 = t0id + 4096;                       // chain set 1
    const int b0i = c0 >> 9, h0i = c0 & 511;
    const int b1i = c1 >> 9, h1i = c1 & 511;

    const float* ip0 = Hbuf   + (size_t)b0i * T_ * H_ + h0i;
    const float* ip1 = Hbuf   + (size_t)b1i * T_ * H_ + h1i;
    float*       sp0 = spikes + (size_t)b0i * T_ * H_ + h0i;
    float*       sp1 = spikes + (size_t)b1i * T_ * H_ + h1i;

    float bufA0[SPF], bufB0[SPF], bufA1[SPF], bufB1[SPF];
#pragma unroll
    for (int j = 0; j < SPF; ++j) {
        bufA0[j] = ip0[(size_t)j * H_];
        bufA1[j] = ip1[(size_t)j * H_];
    }

    float v0 = 0.0f, th0 = 1.0f, v1 = 0.0f, th1 = 1.0f;
    for (int t0 = 0; t0 < T_; t0 += 2 * SPF) {        // 64 iters, no tail
#pragma unroll
        for (int j = 0; j < SPF; ++j) {
            bufB0[j] = ip0[(size_t)(t0 + SPF + j) * H_];
            bufB1[j] = ip1[(size_t)(t0 + SPF + j) * H_];
        }
        asm volatile("" ::: "memory");
        scan_steps2(bufA0, bufA1, sp0, sp1, t0, v0, th0, v1, th1);

        if (t0 + 2 * SPF < T_) {
#pragma unroll
            for (int j = 0; j < SPF; ++j) {
                bufA0[j] = ip0[(size_t)(t0 + 2 * SPF + j) * H_];
                bufA1[j] = ip1[(size_t)(t0 + 2 * SPF + j) * H_];
            }
        }
        asm volatile("" ::: "memory");
        scan_steps2(bufB0, bufB1, sp0, sp1, t0 + SPF, v0, th0, v1, th1);
    }
    vout[c0]  = v0;  thout[c0] = th0;
    vout[c1]  = v1;  thout[c1] = th1;
}

// ---------------------------------------------------------------------------
extern "C" void kernel_launch(void* const* d_in, const int* in_sizes, int n_in,
                              void* d_out, int out_size, void* d_ws, size_t ws_size,
                              hipStream_t stream) {
    const float* x    = (const float*)d_in[0];   // [16, 2048, 512]
    const float* W    = (const float*)d_in[1];   // [512, 512]
    const float* bias = (const float*)d_in[2];   // [512]

    float* out    = (float*)d_out;
    float* spikes = out;
    float* v_f    = out + (size_t)M_ * H_;
    float* th_f   = v_f + (size_t)B_ * H_;

    float* hbuf   = (float*)d_ws;                // 64 MiB scratch for h

    dim3 grid(M_ / BM, H_ / BN);                 // 256 x 4
    gemm_xwT<<<grid, 256, 0, stream>>>(x, W, bias, hbuf);
    gif_scan<<<4096 / 64, 64, 0, stream>>>(hbuf, spikes, v_f, th_f);
}